// Round 19
// baseline (92.543 us; speedup 1.0000x reference)
//
#include <hip/hip_runtime.h>
#include <cstdint>

typedef uint16_t u16;
typedef __attribute__((ext_vector_type(8))) short short8;
typedef __attribute__((ext_vector_type(4))) float f32x4;

__device__ __forceinline__ u16 f2bf(float f) {
  uint32_t u = __float_as_uint(f);
  u += 0x7fff + ((u >> 16) & 1);   // RNE
  return (u16)(u >> 16);
}
__device__ __forceinline__ uint32_t pk2bf(float a, float b) {
  uint32_t ua = __float_as_uint(a) + 0x8000u;
  uint32_t ub = __float_as_uint(b) + 0x8000u;
  return (ua >> 16) | (ub & 0xFFFF0000u);
}

#define GLL16(gp, lp) __builtin_amdgcn_global_load_lds( \
    (__attribute__((address_space(1))) void*)(gp), \
    (__attribute__((address_space(3))) void*)(lp), 16, 0, 0)

#define SBAR()       __builtin_amdgcn_s_barrier()
#define WAIT_LGKM0() asm volatile("s_waitcnt lgkmcnt(0)" ::: "memory")
#define WAIT_VM(N)   asm volatile("s_waitcnt vmcnt(" #N ")" ::: "memory")
#define MEMBAR()     asm volatile("" ::: "memory")

// vmcnt immediate must be a literal in the asm string -> if constexpr dispatch
template<int N> __device__ __forceinline__ void wait_vm() {
  static_assert(N == 0 || N == 4 || N == 6 || N == 8 || N == 10 || N == 12, "add literal case");
  if constexpr (N == 0)  { WAIT_VM(0); }
  else if constexpr (N == 4)  { WAIT_VM(4); }
  else if constexpr (N == 6)  { WAIT_VM(6); }
  else if constexpr (N == 8)  { WAIT_VM(8); }
  else if constexpr (N == 10) { WAIT_VM(10); }
  else if constexpr (N == 12) { WAIT_VM(12); }
}

// ---------------- fused f32 -> bf16 convert; Wq pre-scaled by d^-0.5 * log2(e) ----------------
__global__ void cvt_all(const float* __restrict__ x,  const float* __restrict__ wq,
                        const float* __restrict__ wk, const float* __restrict__ wv,
                        const float* __restrict__ wo,
                        u16* __restrict__ xb, u16* __restrict__ wcat, u16* __restrict__ wob) {
  int i = blockIdx.x * 256 + threadIdx.x;
  const float4* src; ushort4* dst; int off; float sc = 1.0f;
  if (i < 1048576)      { src = (const float4*)x;  dst = (ushort4*)xb;              off = i; }
  else if (i < 1310720) { src = (const float4*)wq; dst = (ushort4*)wcat;            off = i - 1048576;
                          sc = 0.18033688011112042f; }   // 0.125 * log2(e)
  else if (i < 1572864) { src = (const float4*)wk; dst = (ushort4*)wcat + 262144;   off = i - 1310720; }
  else if (i < 1835008) { src = (const float4*)wv; dst = (ushort4*)wcat + 524288;   off = i - 1572864; }
  else                  { src = (const float4*)wo; dst = (ushort4*)wob;             off = i - 1835008; }
  float4 v = src[off];
  ushort4 o;
  o.x = f2bf(v.x * sc); o.y = f2bf(v.y * sc); o.z = f2bf(v.z * sc); o.w = f2bf(v.w * sc);
  dst[off] = o;
}

// ---------------- BMxBN counted-vmcnt GEMM (unchanged from round 16) ----------------
template<int BM, int BN, int OUT_BF16>
__global__ __launch_bounds__(256, 2) void gemm_t(const u16* __restrict__ A,
                                                 const u16* __restrict__ B,
                                                 void* __restrict__ Cout,
                                                 int N, int K, int ntN) {
  constexpr int MF = BM / 32;
  constexpr int NF = BN / 32;
  constexpr int G  = (BM + BN) / 32;
  __shared__ u16 smA[2][BM * 64];
  __shared__ u16 smB[2][BN * 64];
  const int tid  = threadIdx.x;
  const int lane = tid & 63, w = tid >> 6;
  const int wr = w >> 1, wc = w & 1;
  const int g = lane >> 4, lr = lane & 15;

  const int cpx = gridDim.x >> 3;
  const int id  = blockIdx.x;
  const int sw  = (id & 7) * cpx + (id >> 3);
  const int row0 = (sw / ntN) * BM, col0 = (sw % ntN) * BN;
  const int T = K >> 6;

  f32x4 acc[MF][NF];
  #pragma unroll
  for (int i = 0; i < MF; ++i)
    #pragma unroll
    for (int j = 0; j < NF; ++j) acc[i][j] = (f32x4){0.f, 0.f, 0.f, 0.f};

  auto STAGE = [&](int kt, int bufi) {
    #pragma unroll
    for (int j = 0; j < BM / 32; ++j) {
      int r  = j * 32 + w * 8 + (lane >> 3);
      int sb = ((lane & 7) << 4) ^ ((r & 7) << 4);
      GLL16(A + (size_t)(row0 + r) * K + kt * 64 + (sb >> 1),
            &smA[bufi][(size_t)(j * 32 + w * 8) * 64]);
    }
    #pragma unroll
    for (int j = 0; j < BN / 32; ++j) {
      int r  = j * 32 + w * 8 + (lane >> 3);
      int sb = ((lane & 7) << 4) ^ ((r & 7) << 4);
      GLL16(B + (size_t)(col0 + r) * K + kt * 64 + (sb >> 1),
            &smB[bufi][(size_t)(j * 32 + w * 8) * 64]);
    }
  };

  STAGE(0, 0); STAGE(1, 1);
  wait_vm<G>(); SBAR(); MEMBAR();

  for (int t = 0; t < T; ++t) {
    const int cur = t & 1;
    short8 a[MF][2], b[NF][2];
    #pragma unroll
    for (int mm = 0; mm < MF; ++mm)
      #pragma unroll
      for (int kh = 0; kh < 2; ++kh) {
        int row = wr * (BM / 2) + mm * 16 + lr;
        int col = (kh * 64 + g * 16) ^ ((row & 7) << 4);
        a[mm][kh] = *(const short8*)((const char*)&smA[cur][0] + row * 128 + col);
      }
    #pragma unroll
    for (int nn = 0; nn < NF; ++nn)
      #pragma unroll
      for (int kh = 0; kh < 2; ++kh) {
        int row = wc * (BN / 2) + nn * 16 + lr;
        int col = (kh * 64 + g * 16) ^ ((row & 7) << 4);
        b[nn][kh] = *(const short8*)((const char*)&smB[cur][0] + row * 128 + col);
      }
    WAIT_LGKM0(); MEMBAR(); SBAR(); MEMBAR();

    if (t + 2 < T) STAGE(t + 2, cur);

    __builtin_amdgcn_s_setprio(1);
    #pragma unroll
    for (int kh = 0; kh < 2; ++kh)
      #pragma unroll
      for (int mm = 0; mm < MF; ++mm)
        #pragma unroll
        for (int nn = 0; nn < NF; ++nn)
          acc[mm][nn] = __builtin_amdgcn_mfma_f32_16x16x32_bf16(
              a[mm][kh], b[nn][kh], acc[mm][nn], 0, 0, 0);
    __builtin_amdgcn_s_setprio(0);

    if (t + 1 < T) {
      if (t + 2 < T) { wait_vm<G>(); } else { wait_vm<0>(); }
      SBAR(); MEMBAR();
    }
  }

  #pragma unroll
  for (int i = 0; i < MF; ++i)
    #pragma unroll
    for (int j = 0; j < NF; ++j)
      #pragma unroll
      for (int ri = 0; ri < 4; ++ri) {
        int rr = row0 + wr * (BM / 2) + i * 16 + g * 4 + ri;
        int cc = col0 + wc * (BN / 2) + j * 16 + lr;
        if (OUT_BF16) ((u16*)Cout)[(size_t)rr * N + cc] = f2bf(acc[i][j][ri]);
        else          ((float*)Cout)[(size_t)rr * N + cc] = acc[i][j][ri];
      }
}

// ---------------- Flash sliding-window attention (v11: v9 + forced 6 waves/SIMD) ----------------
// 8 waves x 16 queries, round-12 schedule (barrier before PV, per-wave skip). LDS 51,200 B
// (pitch 68: row stride 34 dwords -> 2 lanes/bank on b128 reads = free) -> 3 blocks/CU;
// __launch_bounds__(512,6) caps VGPR at 85 so the 3rd block actually fits (24 waves/CU).
__global__ __launch_bounds__(512, 6) void attn_swa(const u16* __restrict__ QKV, u16* __restrict__ O) {
  const int S = 2048;
  const int qb = blockIdx.x * 128;
  const int b = blockIdx.y >> 4, h = blockIdx.y & 15;
  const int tid = threadIdx.x;
  const int lane = tid & 63, w = tid >> 6;           // w in 0..7
  const int g = lane >> 4, lr = lane & 15;

  __shared__ u16 Klds[2][64 * 64];   // [64 keys][64 d], rows 128B, byte ^= (row&7)<<4
  __shared__ u16 Vt[2][64][68];      // V^T [d][key], pitch 136B
  __shared__ u16 Plds[8][16][68];    // per-wave P^T [q][key 0..63], pitch 136B

  const u16* Qb = QKV + (size_t)b * S * 3072 + h * 64;
  const u16* Kb = QKV + (size_t)b * S * 3072 + 1024 + h * 64;
  const u16* Vb = QKV + (size_t)b * S * 3072 + 2048 + h * 64;

  const int qw = qb + w * 16;
  short8 qf[2];
  #pragma unroll
  for (int kh = 0; kh < 2; ++kh)
    qf[kh] = *(const short8*)(Qb + (size_t)(qw + lr) * 3072 + kh * 32 + g * 8);

  float ls = 0.f;
  f32x4 accO[4];
  #pragma unroll
  for (int i = 0; i < 4; ++i) accO[i] = (f32x4){0.f, 0.f, 0.f, 0.f};

  int ks = qb - 511; if (ks < 0) ks = 0; ks &= ~63;
  const int ke = qb + 127;
  const int nt = ((ke - ks) >> 6) + 1;

  short8 vreg;   // V in flight: key = lane, d = w*8 .. w*8+7

  auto STAGE_K = [&](int kb, int buf) {
    int r  = w * 8 + (lane >> 3);                    // 8 waves x 8 rows = 64 keys
    int sb = ((lane & 7) << 4) ^ ((r & 7) << 4);
    const u16* gp = Kb + (size_t)(kb + r) * 3072 + (sb >> 1);
    u16* lp = Klds[buf] + w * 512;                   // wave-uniform base (8 rows x 128B)
    GLL16(gp, lp);
  };
  auto LOAD_V = [&](int kb) {
    vreg = *(const short8*)(Vb + (size_t)(kb + lane) * 3072 + w * 8);
  };
  auto WRITE_V = [&](int buf) {
    #pragma unroll
    for (int j = 0; j < 8; ++j) Vt[buf][w * 8 + j][lane] = (u16)vreg[j];
  };

  // prologue: stage tile 0; publish Klds[0]; Vt[0] written post-barrier (published at B0)
  LOAD_V(ks); MEMBAR();
  STAGE_K(ks, 0); MEMBAR();
  WAIT_VM(0); MEMBAR();
  SBAR(); MEMBAR();
  WRITE_V(0);

  int cur = 0, kb = ks;
  for (int t = 0; t < nt; ++t, kb += 64) {
    const int nxt = cur ^ 1;
    const bool more = (t + 1 < nt);
    if (more) { LOAD_V(kb + 64); MEMBAR(); STAGE_K(kb + 64, nxt); MEMBAR(); }

    // per-wave compute skip: tile outside [qw-511, qw+15] contributes only masked zeros
    const bool active = (kb <= qw + 15) && (kb + 63 >= qw - 511);
    if (active) {
      // ---- QK^T (swapped): 4 key-subtiles x 2 MFMAs over d=64 ----
      float p[4][4];
      #pragma unroll
      for (int st = 0; st < 4; ++st) {
        f32x4 c4 = (f32x4){0.f, 0.f, 0.f, 0.f};
        int r = st * 16 + lr;
        int swz = (r & 7) << 4;
        const char* krow = (const char*)(Klds[cur]) + r * 128;
        short8 kf0 = *(const short8*)(krow + ((g * 16) ^ swz));
        short8 kf1 = *(const short8*)(krow + ((64 + g * 16) ^ swz));
        __builtin_amdgcn_s_setprio(1);
        c4 = __builtin_amdgcn_mfma_f32_16x16x32_bf16(kf0, qf[0], c4, 0, 0, 0);
        c4 = __builtin_amdgcn_mfma_f32_16x16x32_bf16(kf1, qf[1], c4, 0, 0, 0);
        __builtin_amdgcn_s_setprio(0);
        #pragma unroll
        for (int ri = 0; ri < 4; ++ri) p[st][ri] = c4[ri];
      }

      // ---- exp2 + mask (clean fast path) + row sum + P^T -> LDS ----
      const bool clean = (kb + 63 <= qw) && (qw + 15 - kb < 512);
      if (clean) {
        #pragma unroll
        for (int st = 0; st < 4; ++st)
          #pragma unroll
          for (int ri = 0; ri < 4; ++ri)
            p[st][ri] = __builtin_amdgcn_exp2f(p[st][ri]);
      } else {
        const int base = qw + lr - kb;
        #pragma unroll
        for (int st = 0; st < 4; ++st)
          #pragma unroll
          for (int ri = 0; ri < 4; ++ri) {
            float e = __builtin_amdgcn_exp2f(p[st][ri]);
            p[st][ri] = ((uint32_t)(base - (st * 16 + g * 4 + ri)) < 512u) ? e : 0.f;
          }
      }
      {
        float s = 0.f;
        #pragma unroll
        for (int st = 0; st < 4; ++st)
          #pragma unroll
          for (int ri = 0; ri < 4; ++ri) s += p[st][ri];
        s += __shfl_xor(s, 16);
        s += __shfl_xor(s, 32);
        ls += s;
      }
      #pragma unroll
      for (int st = 0; st < 4; ++st) {
        uint2 u2;
        u2.x = pk2bf(p[st][0], p[st][1]);
        u2.y = pk2bf(p[st][2], p[st][3]);
        *(uint2*)(&Plds[w][lr][st * 16 + g * 4]) = u2;
      }
    }

    // ---- mid-tile sync: K(t+1)+V(t+1) landed + own ds ops drained -> ONE barrier ----
    if (more) { WAIT_VM(0); MEMBAR(); }
    WAIT_LGKM0(); MEMBAR();
    SBAR(); MEMBAR();            // publishes Klds[nxt], Vt[cur] (prev iter), Plds
    if (more) WRITE_V(nxt);      // post-barrier: touches only Vt[nxt]

    if (active) {
      // ---- PV: A = P^T, B = V^T[cur] ----
      short8 pf0 = *(const short8*)(&Plds[w][lr][g * 8]);
      short8 pf1 = *(const short8*)(&Plds[w][lr][32 + g * 8]);
      __builtin_amdgcn_s_setprio(1);
      #pragma unroll
      for (int dt = 0; dt < 4; ++dt) {
        short8 vf0 = *(const short8*)(&Vt[cur][dt * 16 + lr][g * 8]);
        short8 vf1 = *(const short8*)(&Vt[cur][dt * 16 + lr][32 + g * 8]);
        accO[dt] = __builtin_amdgcn_mfma_f32_16x16x32_bf16(pf0, vf0, accO[dt], 0, 0, 0);
        accO[dt] = __builtin_amdgcn_mfma_f32_16x16x32_bf16(pf1, vf1, accO[dt], 0, 0, 0);
      }
      __builtin_amdgcn_s_setprio(0);
    }
    cur = nxt;
  }

  float lsq[4];
  #pragma unroll
  for (int ri = 0; ri < 4; ++ri) lsq[ri] = __shfl(ls, g * 4 + ri);
  #pragma unroll
  for (int dt = 0; dt < 4; ++dt)
    #pragma unroll
    for (int ri = 0; ri < 4; ++ri) {
      int qi = qw + g * 4 + ri;
      O[(size_t)(b * S + qi) * 1024 + h * 64 + dt * 16 + lr] = f2bf(accO[dt][ri] / lsq[ri]);
    }
}

// ---------------- launch ----------------
extern "C" void kernel_launch(void* const* d_in, const int* in_sizes, int n_in,
                              void* d_out, int out_size, void* d_ws, size_t ws_size,
                              hipStream_t stream) {
  const float* x  = (const float*)d_in[0];
  const float* Wq = (const float*)d_in[1];
  const float* Wk = (const float*)d_in[2];
  const float* Wv = (const float*)d_in[3];
  const float* Wo = (const float*)d_in[4];

  char* ws = (char*)d_ws;
  u16* xb   = (u16*)(ws);                    //  8 MiB: x bf16 [4096][1024]
  u16* Wcat = (u16*)(ws + (8  << 20));       //  6 MiB: [Wq;Wk;Wv] bf16 [3072][1024]
  u16* Wob  = (u16*)(ws + (14 << 20));       //  2 MiB: Wo bf16 [1024][1024]
  u16* QKV  = (u16*)(ws + (16 << 20));       // 24 MiB: [4096][3072]
  u16* Oatt = (u16*)(ws + (40 << 20));       //  8 MiB: [4096][1024]

  cvt_all<<<8192, 256, 0, stream>>>(x, Wq, Wk, Wv, Wo, xb, Wcat, Wob);
  gemm_t<128, 192, 1><<<512, 256, 0, stream>>>(xb, Wcat, QKV, 3072, 1024, 16);
  attn_swa<<<dim3(16, 32), 512, 0, stream>>>(QKV, Oatt);
  gemm_t<64, 128, 0><<<512, 256, 0, stream>>>(Oatt, Wob, d_out, 1024, 1024, 8);
}

// Round 20
// 82.099 us; speedup vs baseline: 1.1272x; 1.1272x over previous
//
#include <hip/hip_runtime.h>
#include <cstdint>

typedef uint16_t u16;
typedef __attribute__((ext_vector_type(8))) short short8;
typedef __attribute__((ext_vector_type(4))) float f32x4;

__device__ __forceinline__ u16 f2bf(float f) {
  uint32_t u = __float_as_uint(f);
  u += 0x7fff + ((u >> 16) & 1);   // RNE
  return (u16)(u >> 16);
}
__device__ __forceinline__ uint32_t pk2bf(float a, float b) {
  uint32_t ua = __float_as_uint(a) + 0x8000u;
  uint32_t ub = __float_as_uint(b) + 0x8000u;
  return (ua >> 16) | (ub & 0xFFFF0000u);
}

#define GLL16(gp, lp) __builtin_amdgcn_global_load_lds( \
    (__attribute__((address_space(1))) void*)(gp), \
    (__attribute__((address_space(3))) void*)(lp), 16, 0, 0)

#define SBAR()       __builtin_amdgcn_s_barrier()
#define WAIT_LGKM0() asm volatile("s_waitcnt lgkmcnt(0)" ::: "memory")
#define WAIT_VM(N)   asm volatile("s_waitcnt vmcnt(" #N ")" ::: "memory")
#define MEMBAR()     asm volatile("" ::: "memory")

// vmcnt immediate must be a literal in the asm string -> if constexpr dispatch
template<int N> __device__ __forceinline__ void wait_vm() {
  static_assert(N == 0 || N == 4 || N == 6 || N == 8 || N == 10 || N == 12, "add literal case");
  if constexpr (N == 0)  { WAIT_VM(0); }
  else if constexpr (N == 4)  { WAIT_VM(4); }
  else if constexpr (N == 6)  { WAIT_VM(6); }
  else if constexpr (N == 8)  { WAIT_VM(8); }
  else if constexpr (N == 10) { WAIT_VM(10); }
  else if constexpr (N == 12) { WAIT_VM(12); }
}

// ---------------- fused f32 -> bf16 convert; Wq pre-scaled by d^-0.5 * log2(e) ----------------
__global__ void cvt_all(const float* __restrict__ x,  const float* __restrict__ wq,
                        const float* __restrict__ wk, const float* __restrict__ wv,
                        const float* __restrict__ wo,
                        u16* __restrict__ xb, u16* __restrict__ wcat, u16* __restrict__ wob) {
  int i = blockIdx.x * 256 + threadIdx.x;
  const float4* src; ushort4* dst; int off; float sc = 1.0f;
  if (i < 1048576)      { src = (const float4*)x;  dst = (ushort4*)xb;              off = i; }
  else if (i < 1310720) { src = (const float4*)wq; dst = (ushort4*)wcat;            off = i - 1048576;
                          sc = 0.18033688011112042f; }   // 0.125 * log2(e)
  else if (i < 1572864) { src = (const float4*)wk; dst = (ushort4*)wcat + 262144;   off = i - 1310720; }
  else if (i < 1835008) { src = (const float4*)wv; dst = (ushort4*)wcat + 524288;   off = i - 1572864; }
  else                  { src = (const float4*)wo; dst = (ushort4*)wob;             off = i - 1835008; }
  float4 v = src[off];
  ushort4 o;
  o.x = f2bf(v.x * sc); o.y = f2bf(v.y * sc); o.z = f2bf(v.z * sc); o.w = f2bf(v.w * sc);
  dst[off] = o;
}

// ---------------- BMxBN counted-vmcnt GEMM (unchanged from round 16) ----------------
template<int BM, int BN, int OUT_BF16>
__global__ __launch_bounds__(256, 2) void gemm_t(const u16* __restrict__ A,
                                                 const u16* __restrict__ B,
                                                 void* __restrict__ Cout,
                                                 int N, int K, int ntN) {
  constexpr int MF = BM / 32;
  constexpr int NF = BN / 32;
  constexpr int G  = (BM + BN) / 32;
  __shared__ u16 smA[2][BM * 64];
  __shared__ u16 smB[2][BN * 64];
  const int tid  = threadIdx.x;
  const int lane = tid & 63, w = tid >> 6;
  const int wr = w >> 1, wc = w & 1;
  const int g = lane >> 4, lr = lane & 15;

  const int cpx = gridDim.x >> 3;
  const int id  = blockIdx.x;
  const int sw  = (id & 7) * cpx + (id >> 3);
  const int row0 = (sw / ntN) * BM, col0 = (sw % ntN) * BN;
  const int T = K >> 6;

  f32x4 acc[MF][NF];
  #pragma unroll
  for (int i = 0; i < MF; ++i)
    #pragma unroll
    for (int j = 0; j < NF; ++j) acc[i][j] = (f32x4){0.f, 0.f, 0.f, 0.f};

  auto STAGE = [&](int kt, int bufi) {
    #pragma unroll
    for (int j = 0; j < BM / 32; ++j) {
      int r  = j * 32 + w * 8 + (lane >> 3);
      int sb = ((lane & 7) << 4) ^ ((r & 7) << 4);
      GLL16(A + (size_t)(row0 + r) * K + kt * 64 + (sb >> 1),
            &smA[bufi][(size_t)(j * 32 + w * 8) * 64]);
    }
    #pragma unroll
    for (int j = 0; j < BN / 32; ++j) {
      int r  = j * 32 + w * 8 + (lane >> 3);
      int sb = ((lane & 7) << 4) ^ ((r & 7) << 4);
      GLL16(B + (size_t)(col0 + r) * K + kt * 64 + (sb >> 1),
            &smB[bufi][(size_t)(j * 32 + w * 8) * 64]);
    }
  };

  STAGE(0, 0); STAGE(1, 1);
  wait_vm<G>(); SBAR(); MEMBAR();

  for (int t = 0; t < T; ++t) {
    const int cur = t & 1;
    short8 a[MF][2], b[NF][2];
    #pragma unroll
    for (int mm = 0; mm < MF; ++mm)
      #pragma unroll
      for (int kh = 0; kh < 2; ++kh) {
        int row = wr * (BM / 2) + mm * 16 + lr;
        int col = (kh * 64 + g * 16) ^ ((row & 7) << 4);
        a[mm][kh] = *(const short8*)((const char*)&smA[cur][0] + row * 128 + col);
      }
    #pragma unroll
    for (int nn = 0; nn < NF; ++nn)
      #pragma unroll
      for (int kh = 0; kh < 2; ++kh) {
        int row = wc * (BN / 2) + nn * 16 + lr;
        int col = (kh * 64 + g * 16) ^ ((row & 7) << 4);
        b[nn][kh] = *(const short8*)((const char*)&smB[cur][0] + row * 128 + col);
      }
    WAIT_LGKM0(); MEMBAR(); SBAR(); MEMBAR();

    if (t + 2 < T) STAGE(t + 2, cur);

    __builtin_amdgcn_s_setprio(1);
    #pragma unroll
    for (int kh = 0; kh < 2; ++kh)
      #pragma unroll
      for (int mm = 0; mm < MF; ++mm)
        #pragma unroll
        for (int nn = 0; nn < NF; ++nn)
          acc[mm][nn] = __builtin_amdgcn_mfma_f32_16x16x32_bf16(
              a[mm][kh], b[nn][kh], acc[mm][nn], 0, 0, 0);
    __builtin_amdgcn_s_setprio(0);

    if (t + 1 < T) {
      if (t + 2 < T) { wait_vm<G>(); } else { wait_vm<0>(); }
      SBAR(); MEMBAR();
    }
  }

  #pragma unroll
  for (int i = 0; i < MF; ++i)
    #pragma unroll
    for (int j = 0; j < NF; ++j)
      #pragma unroll
      for (int ri = 0; ri < 4; ++ri) {
        int rr = row0 + wr * (BM / 2) + i * 16 + g * 4 + ri;
        int cc = col0 + wc * (BN / 2) + j * 16 + lr;
        if (OUT_BF16) ((u16*)Cout)[(size_t)rr * N + cc] = f2bf(acc[i][j][ri]);
        else          ((float*)Cout)[(size_t)rr * N + cc] = acc[i][j][ri];
      }
}

// ---------------- Flash sliding-window attention (v12: v9 sizes + fused per-st softmax) ----------------
// 8 waves x 16 queries, round-12 schedule. Softmax fused into the QK subtile loop:
// c4 -> mask/exp2 -> pack -> Plds per st, shrinking live p[4][4] (16 VGPR) to one c4 (4).
// launch_bounds(512,4): no forced cap (v11's forced 6 -> VGPR 40 -> scratch spills, +16 us).
// If natural VGPR <= 85, HW schedules 3 blocks/CU on its own (LDS 53,248 allows it).
__global__ __launch_bounds__(512, 4) void attn_swa(const u16* __restrict__ QKV, u16* __restrict__ O) {
  const int S = 2048;
  const int qb = blockIdx.x * 128;
  const int b = blockIdx.y >> 4, h = blockIdx.y & 15;
  const int tid = threadIdx.x;
  const int lane = tid & 63, w = tid >> 6;           // w in 0..7
  const int g = lane >> 4, lr = lane & 15;

  __shared__ u16 Klds[2][64 * 64];   // [64 keys][64 d], rows 128B, byte ^= (row&7)<<4
  __shared__ u16 Vt[2][64][72];      // V^T [d][key], pitch 144B
  __shared__ u16 Plds[8][16][72];    // per-wave P^T [q][key 0..63], pitch 144B

  const u16* Qb = QKV + (size_t)b * S * 3072 + h * 64;
  const u16* Kb = QKV + (size_t)b * S * 3072 + 1024 + h * 64;
  const u16* Vb = QKV + (size_t)b * S * 3072 + 2048 + h * 64;

  const int qw = qb + w * 16;
  short8 qf[2];
  #pragma unroll
  for (int kh = 0; kh < 2; ++kh)
    qf[kh] = *(const short8*)(Qb + (size_t)(qw + lr) * 3072 + kh * 32 + g * 8);

  float ls = 0.f;
  f32x4 accO[4];
  #pragma unroll
  for (int i = 0; i < 4; ++i) accO[i] = (f32x4){0.f, 0.f, 0.f, 0.f};

  int ks = qb - 511; if (ks < 0) ks = 0; ks &= ~63;
  const int ke = qb + 127;
  const int nt = ((ke - ks) >> 6) + 1;

  short8 vreg;   // V in flight: key = lane, d = w*8 .. w*8+7

  auto STAGE_K = [&](int kb, int buf) {
    int r  = w * 8 + (lane >> 3);                    // 8 waves x 8 rows = 64 keys
    int sb = ((lane & 7) << 4) ^ ((r & 7) << 4);
    const u16* gp = Kb + (size_t)(kb + r) * 3072 + (sb >> 1);
    u16* lp = Klds[buf] + w * 512;                   // wave-uniform base (8 rows x 128B)
    GLL16(gp, lp);
  };
  auto LOAD_V = [&](int kb) {
    vreg = *(const short8*)(Vb + (size_t)(kb + lane) * 3072 + w * 8);
  };
  auto WRITE_V = [&](int buf) {
    #pragma unroll
    for (int j = 0; j < 8; ++j) Vt[buf][w * 8 + j][lane] = (u16)vreg[j];
  };

  // prologue: stage tile 0; publish Klds[0]; Vt[0] written post-barrier (published at B0)
  LOAD_V(ks); MEMBAR();
  STAGE_K(ks, 0); MEMBAR();
  WAIT_VM(0); MEMBAR();
  SBAR(); MEMBAR();
  WRITE_V(0);

  int cur = 0, kb = ks;
  for (int t = 0; t < nt; ++t, kb += 64) {
    const int nxt = cur ^ 1;
    const bool more = (t + 1 < nt);
    if (more) { LOAD_V(kb + 64); MEMBAR(); STAGE_K(kb + 64, nxt); MEMBAR(); }

    // per-wave compute skip: tile outside [qw-511, qw+15] contributes only masked zeros
    const bool active = (kb <= qw + 15) && (kb + 63 >= qw - 511);
    if (active) {
      const bool clean = (kb + 63 <= qw) && (qw + 15 - kb < 512);
      const int base = qw + lr - kb;
      float s = 0.f;
      // ---- QK^T (swapped) fused with softmax: per key-subtile c4 -> exp2/mask -> pack ----
      #pragma unroll
      for (int st = 0; st < 4; ++st) {
        f32x4 c4 = (f32x4){0.f, 0.f, 0.f, 0.f};
        int r = st * 16 + lr;
        int swz = (r & 7) << 4;
        const char* krow = (const char*)(Klds[cur]) + r * 128;
        short8 kf0 = *(const short8*)(krow + ((g * 16) ^ swz));
        short8 kf1 = *(const short8*)(krow + ((64 + g * 16) ^ swz));
        __builtin_amdgcn_s_setprio(1);
        c4 = __builtin_amdgcn_mfma_f32_16x16x32_bf16(kf0, qf[0], c4, 0, 0, 0);
        c4 = __builtin_amdgcn_mfma_f32_16x16x32_bf16(kf1, qf[1], c4, 0, 0, 0);
        __builtin_amdgcn_s_setprio(0);
        float p0, p1, p2, p3;
        if (clean) {
          p0 = __builtin_amdgcn_exp2f(c4[0]);
          p1 = __builtin_amdgcn_exp2f(c4[1]);
          p2 = __builtin_amdgcn_exp2f(c4[2]);
          p3 = __builtin_amdgcn_exp2f(c4[3]);
        } else {
          p0 = ((uint32_t)(base - (st * 16 + g * 4 + 0)) < 512u) ? __builtin_amdgcn_exp2f(c4[0]) : 0.f;
          p1 = ((uint32_t)(base - (st * 16 + g * 4 + 1)) < 512u) ? __builtin_amdgcn_exp2f(c4[1]) : 0.f;
          p2 = ((uint32_t)(base - (st * 16 + g * 4 + 2)) < 512u) ? __builtin_amdgcn_exp2f(c4[2]) : 0.f;
          p3 = ((uint32_t)(base - (st * 16 + g * 4 + 3)) < 512u) ? __builtin_amdgcn_exp2f(c4[3]) : 0.f;
        }
        s += (p0 + p1) + (p2 + p3);
        uint2 u2;
        u2.x = pk2bf(p0, p1);
        u2.y = pk2bf(p2, p3);
        *(uint2*)(&Plds[w][lr][st * 16 + g * 4]) = u2;
      }
      s += __shfl_xor(s, 16);
      s += __shfl_xor(s, 32);
      ls += s;
    }

    // ---- mid-tile sync: K(t+1)+V(t+1) landed + own ds ops drained -> ONE barrier ----
    if (more) { WAIT_VM(0); MEMBAR(); }
    WAIT_LGKM0(); MEMBAR();
    SBAR(); MEMBAR();            // publishes Klds[nxt], Vt[cur] (prev iter), Plds
    if (more) WRITE_V(nxt);      // post-barrier: touches only Vt[nxt]

    if (active) {
      // ---- PV: A = P^T, B = V^T[cur] ----
      short8 pf0 = *(const short8*)(&Plds[w][lr][g * 8]);
      short8 pf1 = *(const short8*)(&Plds[w][lr][32 + g * 8]);
      __builtin_amdgcn_s_setprio(1);
      #pragma unroll
      for (int dt = 0; dt < 4; ++dt) {
        short8 vf0 = *(const short8*)(&Vt[cur][dt * 16 + lr][g * 8]);
        short8 vf1 = *(const short8*)(&Vt[cur][dt * 16 + lr][32 + g * 8]);
        accO[dt] = __builtin_amdgcn_mfma_f32_16x16x32_bf16(pf0, vf0, accO[dt], 0, 0, 0);
        accO[dt] = __builtin_amdgcn_mfma_f32_16x16x32_bf16(pf1, vf1, accO[dt], 0, 0, 0);
      }
      __builtin_amdgcn_s_setprio(0);
    }
    cur = nxt;
  }

  float lsq[4];
  #pragma unroll
  for (int ri = 0; ri < 4; ++ri) lsq[ri] = __shfl(ls, g * 4 + ri);
  #pragma unroll
  for (int dt = 0; dt < 4; ++dt)
    #pragma unroll
    for (int ri = 0; ri < 4; ++ri) {
      int qi = qw + g * 4 + ri;
      O[(size_t)(b * S + qi) * 1024 + h * 64 + dt * 16 + lr] = f2bf(accO[dt][ri] / lsq[ri]);
    }
}

// ---------------- launch ----------------
extern "C" void kernel_launch(void* const* d_in, const int* in_sizes, int n_in,
                              void* d_out, int out_size, void* d_ws, size_t ws_size,
                              hipStream_t stream) {
  const float* x  = (const float*)d_in[0];
  const float* Wq = (const float*)d_in[1];
  const float* Wk = (const float*)d_in[2];
  const float* Wv = (const float*)d_in[3];
  const float* Wo = (const float*)d_in[4];

  char* ws = (char*)d_ws;
  u16* xb   = (u16*)(ws);                    //  8 MiB: x bf16 [4096][1024]
  u16* Wcat = (u16*)(ws + (8  << 20));       //  6 MiB: [Wq;Wk;Wv] bf16 [3072][1024]
  u16* Wob  = (u16*)(ws + (14 << 20));       //  2 MiB: Wo bf16 [1024][1024]
  u16* QKV  = (u16*)(ws + (16 << 20));       // 24 MiB: [4096][3072]
  u16* Oatt = (u16*)(ws + (40 << 20));       //  8 MiB: [4096][1024]

  cvt_all<<<8192, 256, 0, stream>>>(x, Wq, Wk, Wv, Wo, xb, Wcat, Wob);
  gemm_t<128, 192, 1><<<512, 256, 0, stream>>>(xb, Wcat, QKV, 3072, 1024, 16);
  attn_swa<<<dim3(16, 32), 512, 0, stream>>>(QKV, Oatt);
  gemm_t<64, 128, 0><<<512, 256, 0, stream>>>(Oatt, Wob, d_out, 1024, 1024, 8);
}

// Round 21
// 80.302 us; speedup vs baseline: 1.1524x; 1.0224x over previous
//
#include <hip/hip_runtime.h>
#include <cstdint>

typedef uint16_t u16;
typedef __attribute__((ext_vector_type(8))) short short8;
typedef __attribute__((ext_vector_type(4))) float f32x4;

__device__ __forceinline__ u16 f2bf(float f) {
  uint32_t u = __float_as_uint(f);
  u += 0x7fff + ((u >> 16) & 1);   // RNE
  return (u16)(u >> 16);
}
__device__ __forceinline__ uint32_t pk2bf(float a, float b) {
  uint32_t ua = __float_as_uint(a) + 0x8000u;
  uint32_t ub = __float_as_uint(b) + 0x8000u;
  return (ua >> 16) | (ub & 0xFFFF0000u);
}

#define GLL16(gp, lp) __builtin_amdgcn_global_load_lds( \
    (__attribute__((address_space(1))) void*)(gp), \
    (__attribute__((address_space(3))) void*)(lp), 16, 0, 0)

#define SBAR()       __builtin_amdgcn_s_barrier()
#define WAIT_LGKM0() asm volatile("s_waitcnt lgkmcnt(0)" ::: "memory")
#define WAIT_VM(N)   asm volatile("s_waitcnt vmcnt(" #N ")" ::: "memory")
#define MEMBAR()     asm volatile("" ::: "memory")

// vmcnt immediate must be a literal in the asm string -> if constexpr dispatch
template<int N> __device__ __forceinline__ void wait_vm() {
  static_assert(N == 0 || N == 4 || N == 6 || N == 8 || N == 10 || N == 12, "add literal case");
  if constexpr (N == 0)  { WAIT_VM(0); }
  else if constexpr (N == 4)  { WAIT_VM(4); }
  else if constexpr (N == 6)  { WAIT_VM(6); }
  else if constexpr (N == 8)  { WAIT_VM(8); }
  else if constexpr (N == 10) { WAIT_VM(10); }
  else if constexpr (N == 12) { WAIT_VM(12); }
}

// ---------------- fused f32 -> bf16 convert; Wq pre-scaled by d^-0.5 * log2(e) ----------------
__global__ void cvt_all(const float* __restrict__ x,  const float* __restrict__ wq,
                        const float* __restrict__ wk, const float* __restrict__ wv,
                        const float* __restrict__ wo,
                        u16* __restrict__ xb, u16* __restrict__ wcat, u16* __restrict__ wob) {
  int i = blockIdx.x * 256 + threadIdx.x;
  const float4* src; ushort4* dst; int off; float sc = 1.0f;
  if (i < 1048576)      { src = (const float4*)x;  dst = (ushort4*)xb;              off = i; }
  else if (i < 1310720) { src = (const float4*)wq; dst = (ushort4*)wcat;            off = i - 1048576;
                          sc = 0.18033688011112042f; }   // 0.125 * log2(e)
  else if (i < 1572864) { src = (const float4*)wk; dst = (ushort4*)wcat + 262144;   off = i - 1310720; }
  else if (i < 1835008) { src = (const float4*)wv; dst = (ushort4*)wcat + 524288;   off = i - 1572864; }
  else                  { src = (const float4*)wo; dst = (ushort4*)wob;             off = i - 1835008; }
  float4 v = src[off];
  ushort4 o;
  o.x = f2bf(v.x * sc); o.y = f2bf(v.y * sc); o.z = f2bf(v.z * sc); o.w = f2bf(v.w * sc);
  dst[off] = o;
}

// ---------------- BMxBN counted-vmcnt GEMM (unchanged from round 16) ----------------
template<int BM, int BN, int OUT_BF16>
__global__ __launch_bounds__(256, 2) void gemm_t(const u16* __restrict__ A,
                                                 const u16* __restrict__ B,
                                                 void* __restrict__ Cout,
                                                 int N, int K, int ntN) {
  constexpr int MF = BM / 32;
  constexpr int NF = BN / 32;
  constexpr int G  = (BM + BN) / 32;
  __shared__ u16 smA[2][BM * 64];
  __shared__ u16 smB[2][BN * 64];
  const int tid  = threadIdx.x;
  const int lane = tid & 63, w = tid >> 6;
  const int wr = w >> 1, wc = w & 1;
  const int g = lane >> 4, lr = lane & 15;

  const int cpx = gridDim.x >> 3;
  const int id  = blockIdx.x;
  const int sw  = (id & 7) * cpx + (id >> 3);
  const int row0 = (sw / ntN) * BM, col0 = (sw % ntN) * BN;
  const int T = K >> 6;

  f32x4 acc[MF][NF];
  #pragma unroll
  for (int i = 0; i < MF; ++i)
    #pragma unroll
    for (int j = 0; j < NF; ++j) acc[i][j] = (f32x4){0.f, 0.f, 0.f, 0.f};

  auto STAGE = [&](int kt, int bufi) {
    #pragma unroll
    for (int j = 0; j < BM / 32; ++j) {
      int r  = j * 32 + w * 8 + (lane >> 3);
      int sb = ((lane & 7) << 4) ^ ((r & 7) << 4);
      GLL16(A + (size_t)(row0 + r) * K + kt * 64 + (sb >> 1),
            &smA[bufi][(size_t)(j * 32 + w * 8) * 64]);
    }
    #pragma unroll
    for (int j = 0; j < BN / 32; ++j) {
      int r  = j * 32 + w * 8 + (lane >> 3);
      int sb = ((lane & 7) << 4) ^ ((r & 7) << 4);
      GLL16(B + (size_t)(col0 + r) * K + kt * 64 + (sb >> 1),
            &smB[bufi][(size_t)(j * 32 + w * 8) * 64]);
    }
  };

  STAGE(0, 0); STAGE(1, 1);
  wait_vm<G>(); SBAR(); MEMBAR();

  for (int t = 0; t < T; ++t) {
    const int cur = t & 1;
    short8 a[MF][2], b[NF][2];
    #pragma unroll
    for (int mm = 0; mm < MF; ++mm)
      #pragma unroll
      for (int kh = 0; kh < 2; ++kh) {
        int row = wr * (BM / 2) + mm * 16 + lr;
        int col = (kh * 64 + g * 16) ^ ((row & 7) << 4);
        a[mm][kh] = *(const short8*)((const char*)&smA[cur][0] + row * 128 + col);
      }
    #pragma unroll
    for (int nn = 0; nn < NF; ++nn)
      #pragma unroll
      for (int kh = 0; kh < 2; ++kh) {
        int row = wc * (BN / 2) + nn * 16 + lr;
        int col = (kh * 64 + g * 16) ^ ((row & 7) << 4);
        b[nn][kh] = *(const short8*)((const char*)&smB[cur][0] + row * 128 + col);
      }
    WAIT_LGKM0(); MEMBAR(); SBAR(); MEMBAR();

    if (t + 2 < T) STAGE(t + 2, cur);

    __builtin_amdgcn_s_setprio(1);
    #pragma unroll
    for (int kh = 0; kh < 2; ++kh)
      #pragma unroll
      for (int mm = 0; mm < MF; ++mm)
        #pragma unroll
        for (int nn = 0; nn < NF; ++nn)
          acc[mm][nn] = __builtin_amdgcn_mfma_f32_16x16x32_bf16(
              a[mm][kh], b[nn][kh], acc[mm][nn], 0, 0, 0);
    __builtin_amdgcn_s_setprio(0);

    if (t + 1 < T) {
      if (t + 2 < T) { wait_vm<G>(); } else { wait_vm<0>(); }
      SBAR(); MEMBAR();
    }
  }

  #pragma unroll
  for (int i = 0; i < MF; ++i)
    #pragma unroll
    for (int j = 0; j < NF; ++j)
      #pragma unroll
      for (int ri = 0; ri < 4; ++ri) {
        int rr = row0 + wr * (BM / 2) + i * 16 + g * 4 + ri;
        int cc = col0 + wc * (BN / 2) + j * 16 + lr;
        if (OUT_BF16) ((u16*)Cout)[(size_t)rr * N + cc] = f2bf(acc[i][j][ri]);
        else          ((float*)Cout)[(size_t)rr * N + cc] = acc[i][j][ri];
      }
}

// ---------------- Flash sliding-window attention (v13: v12 + XCD qb-pair swizzle + deferred ls) ----------------
// 8 waves x 16 queries. qb remapped so each XCD owns two CONSECUTIVE qb-tiles per (b,h):
// dispatch xcd = blockIdx.x % 8 (grid.x=16, 16*y = 0 mod 8), so qb_idx = 2*(x&7) + (x>>3)
// makes the ~78%-shared K/V window an L2 hit on the sibling block. ls cross-lane reduce
// deferred to the epilogue (per-tile shuffles removed from the pre-barrier path).
__global__ __launch_bounds__(512, 4) void attn_swa(const u16* __restrict__ QKV, u16* __restrict__ O) {
  const int S = 2048;
  const int qx = blockIdx.x;
  const int qb = (2 * (qx & 7) + (qx >> 3)) * 128;   // bijective for grid.x = 16
  const int b = blockIdx.y >> 4, h = blockIdx.y & 15;
  const int tid = threadIdx.x;
  const int lane = tid & 63, w = tid >> 6;           // w in 0..7
  const int g = lane >> 4, lr = lane & 15;

  __shared__ u16 Klds[2][64 * 64];   // [64 keys][64 d], rows 128B, byte ^= (row&7)<<4
  __shared__ u16 Vt[2][64][72];      // V^T [d][key], pitch 144B
  __shared__ u16 Plds[8][16][72];    // per-wave P^T [q][key 0..63], pitch 144B

  const u16* Qb = QKV + (size_t)b * S * 3072 + h * 64;
  const u16* Kb = QKV + (size_t)b * S * 3072 + 1024 + h * 64;
  const u16* Vb = QKV + (size_t)b * S * 3072 + 2048 + h * 64;

  const int qw = qb + w * 16;
  short8 qf[2];
  #pragma unroll
  for (int kh = 0; kh < 2; ++kh)
    qf[kh] = *(const short8*)(Qb + (size_t)(qw + lr) * 3072 + kh * 32 + g * 8);

  float ls = 0.f;                    // lane-local partial (16 key-slots); reduced in epilogue
  f32x4 accO[4];
  #pragma unroll
  for (int i = 0; i < 4; ++i) accO[i] = (f32x4){0.f, 0.f, 0.f, 0.f};

  int ks = qb - 511; if (ks < 0) ks = 0; ks &= ~63;
  const int ke = qb + 127;
  const int nt = ((ke - ks) >> 6) + 1;

  short8 vreg;   // V in flight: key = lane, d = w*8 .. w*8+7

  auto STAGE_K = [&](int kb, int buf) {
    int r  = w * 8 + (lane >> 3);                    // 8 waves x 8 rows = 64 keys
    int sb = ((lane & 7) << 4) ^ ((r & 7) << 4);
    const u16* gp = Kb + (size_t)(kb + r) * 3072 + (sb >> 1);
    u16* lp = Klds[buf] + w * 512;                   // wave-uniform base (8 rows x 128B)
    GLL16(gp, lp);
  };
  auto LOAD_V = [&](int kb) {
    vreg = *(const short8*)(Vb + (size_t)(kb + lane) * 3072 + w * 8);
  };
  auto WRITE_V = [&](int buf) {
    #pragma unroll
    for (int j = 0; j < 8; ++j) Vt[buf][w * 8 + j][lane] = (u16)vreg[j];
  };

  // prologue: stage tile 0; publish Klds[0]; Vt[0] written post-barrier (published at B0)
  LOAD_V(ks); MEMBAR();
  STAGE_K(ks, 0); MEMBAR();
  WAIT_VM(0); MEMBAR();
  SBAR(); MEMBAR();
  WRITE_V(0);

  int cur = 0, kb = ks;
  for (int t = 0; t < nt; ++t, kb += 64) {
    const int nxt = cur ^ 1;
    const bool more = (t + 1 < nt);
    if (more) { LOAD_V(kb + 64); MEMBAR(); STAGE_K(kb + 64, nxt); MEMBAR(); }

    // per-wave compute skip: tile outside [qw-511, qw+15] contributes only masked zeros
    const bool active = (kb <= qw + 15) && (kb + 63 >= qw - 511);
    if (active) {
      const bool clean = (kb + 63 <= qw) && (qw + 15 - kb < 512);
      const int base = qw + lr - kb;
      // ---- QK^T (swapped) fused with softmax: per key-subtile c4 -> exp2/mask -> pack ----
      #pragma unroll
      for (int st = 0; st < 4; ++st) {
        f32x4 c4 = (f32x4){0.f, 0.f, 0.f, 0.f};
        int r = st * 16 + lr;
        int swz = (r & 7) << 4;
        const char* krow = (const char*)(Klds[cur]) + r * 128;
        short8 kf0 = *(const short8*)(krow + ((g * 16) ^ swz));
        short8 kf1 = *(const short8*)(krow + ((64 + g * 16) ^ swz));
        __builtin_amdgcn_s_setprio(1);
        c4 = __builtin_amdgcn_mfma_f32_16x16x32_bf16(kf0, qf[0], c4, 0, 0, 0);
        c4 = __builtin_amdgcn_mfma_f32_16x16x32_bf16(kf1, qf[1], c4, 0, 0, 0);
        __builtin_amdgcn_s_setprio(0);
        float p0, p1, p2, p3;
        if (clean) {
          p0 = __builtin_amdgcn_exp2f(c4[0]);
          p1 = __builtin_amdgcn_exp2f(c4[1]);
          p2 = __builtin_amdgcn_exp2f(c4[2]);
          p3 = __builtin_amdgcn_exp2f(c4[3]);
        } else {
          p0 = ((uint32_t)(base - (st * 16 + g * 4 + 0)) < 512u) ? __builtin_amdgcn_exp2f(c4[0]) : 0.f;
          p1 = ((uint32_t)(base - (st * 16 + g * 4 + 1)) < 512u) ? __builtin_amdgcn_exp2f(c4[1]) : 0.f;
          p2 = ((uint32_t)(base - (st * 16 + g * 4 + 2)) < 512u) ? __builtin_amdgcn_exp2f(c4[2]) : 0.f;
          p3 = ((uint32_t)(base - (st * 16 + g * 4 + 3)) < 512u) ? __builtin_amdgcn_exp2f(c4[3]) : 0.f;
        }
        ls += (p0 + p1) + (p2 + p3);   // lane-local; cross-lane reduce deferred
        uint2 u2;
        u2.x = pk2bf(p0, p1);
        u2.y = pk2bf(p2, p3);
        *(uint2*)(&Plds[w][lr][st * 16 + g * 4]) = u2;
      }
    }

    // ---- mid-tile sync: K(t+1)+V(t+1) landed + own ds ops drained -> ONE barrier ----
    if (more) { WAIT_VM(0); MEMBAR(); }
    WAIT_LGKM0(); MEMBAR();
    SBAR(); MEMBAR();            // publishes Klds[nxt], Vt[cur] (prev iter), Plds
    if (more) WRITE_V(nxt);      // post-barrier: touches only Vt[nxt]

    if (active) {
      // ---- PV: A = P^T, B = V^T[cur] ----
      short8 pf0 = *(const short8*)(&Plds[w][lr][g * 8]);
      short8 pf1 = *(const short8*)(&Plds[w][lr][32 + g * 8]);
      __builtin_amdgcn_s_setprio(1);
      #pragma unroll
      for (int dt = 0; dt < 4; ++dt) {
        short8 vf0 = *(const short8*)(&Vt[cur][dt * 16 + lr][g * 8]);
        short8 vf1 = *(const short8*)(&Vt[cur][dt * 16 + lr][32 + g * 8]);
        accO[dt] = __builtin_amdgcn_mfma_f32_16x16x32_bf16(pf0, vf0, accO[dt], 0, 0, 0);
        accO[dt] = __builtin_amdgcn_mfma_f32_16x16x32_bf16(pf1, vf1, accO[dt], 0, 0, 0);
      }
      __builtin_amdgcn_s_setprio(0);
    }
    cur = nxt;
  }

  // epilogue: finish ls reduce across the 4 g-groups, then normalize + store
  ls += __shfl_xor(ls, 16);
  ls += __shfl_xor(ls, 32);
  float lsq[4];
  #pragma unroll
  for (int ri = 0; ri < 4; ++ri) lsq[ri] = __shfl(ls, g * 4 + ri);
  #pragma unroll
  for (int dt = 0; dt < 4; ++dt)
    #pragma unroll
    for (int ri = 0; ri < 4; ++ri) {
      int qi = qw + g * 4 + ri;
      O[(size_t)(b * S + qi) * 1024 + h * 64 + dt * 16 + lr] = f2bf(accO[dt][ri] / lsq[ri]);
    }
}

// ---------------- launch ----------------
extern "C" void kernel_launch(void* const* d_in, const int* in_sizes, int n_in,
                              void* d_out, int out_size, void* d_ws, size_t ws_size,
                              hipStream_t stream) {
  const float* x  = (const float*)d_in[0];
  const float* Wq = (const float*)d_in[1];
  const float* Wk = (const float*)d_in[2];
  const float* Wv = (const float*)d_in[3];
  const float* Wo = (const float*)d_in[4];

  char* ws = (char*)d_ws;
  u16* xb   = (u16*)(ws);                    //  8 MiB: x bf16 [4096][1024]
  u16* Wcat = (u16*)(ws + (8  << 20));       //  6 MiB: [Wq;Wk;Wv] bf16 [3072][1024]
  u16* Wob  = (u16*)(ws + (14 << 20));       //  2 MiB: Wo bf16 [1024][1024]
  u16* QKV  = (u16*)(ws + (16 << 20));       // 24 MiB: [4096][3072]
  u16* Oatt = (u16*)(ws + (40 << 20));       //  8 MiB: [4096][1024]

  cvt_all<<<8192, 256, 0, stream>>>(x, Wq, Wk, Wv, Wo, xb, Wcat, Wob);
  gemm_t<128, 192, 1><<<512, 256, 0, stream>>>(xb, Wcat, QKV, 3072, 1024, 16);
  attn_swa<<<dim3(16, 32), 512, 0, stream>>>(QKV, Oatt);
  gemm_t<64, 128, 0><<<512, 256, 0, stream>>>(Oatt, Wob, d_out, 1024, 1024, 8);
}